// Round 8
// baseline (186.919 us; speedup 1.0000x reference)
//
#include <hip/hip_runtime.h>
#include <hip/hip_bf16.h>
#include <math.h>

#define IN_DIM 128
#define HID 128
#define HEADS 8
#define OUT_DIM 64
#define SLOPE 0.2f
#define BSHIFT 7          // 128 nodes per bucket
#define BCAP 4096         // entries per bucket (mean ~2176)
#define BCAPSHIFT 12
#define EPT 8             // edges per thread in bscatter

typedef short bf16x8 __attribute__((ext_vector_type(8)));
typedef float f32x4 __attribute__((ext_vector_type(4)));

__device__ __forceinline__ float lrelu(float x) { return fmaxf(x, SLOPE * x); }
__device__ __forceinline__ float bf2f(unsigned u) { return __uint_as_float(u << 16); }
__device__ __forceinline__ unsigned short f2bf(float f) {
    unsigned u = __float_as_uint(f);
    return (unsigned short)((u + 0x7FFF + ((u >> 16) & 1)) >> 16);  // RNE
}

// ---------------- setup: zero gcursor + build bf16 transposed weights --------
__global__ __launch_bounds__(256) void setup_kernel(
    const float* __restrict__ W1, const float* __restrict__ W2,
    short* __restrict__ w1t, short* __restrict__ w2t, int* __restrict__ gcursor) {
    int t = threadIdx.x;
    int b = blockIdx.x;
    if (b == 96) {
        for (int i = t; i < 512; i += 256) gcursor[i] = 0;
        return;
    }
    if (b < 64) {
        int id = b * 256 + t;            // id = n*128 + k
        int n = id >> 7, k = id & 127;
        w1t[id] = (short)f2bf(W1[k * 128 + n]);
    } else {
        int id = (b - 64) * 256 + t;     // id = n*128 + k, n < 64
        int n = id >> 7, k = id & 127;
        w2t[id] = (short)f2bf(W2[k * 64 + n]);
    }
}

// ---------------- K1 path A: bucket scatter with block-local counting sort ---
__device__ __forceinline__ void bscatter_body(
    int blk, int* smem, const int* __restrict__ idx,
    int* __restrict__ gcursor, unsigned* __restrict__ bucket_buf,
    int E, int N, int NB) {
    int* hist  = smem;
    int* gbase = smem + 512;
    int* lbase = smem + 1024;
    int* wtot  = smem + 1536;
    int* misc  = smem + 1540;     // [0]=total, [1]=nz
    unsigned* sent = (unsigned*)(smem + 1552);
    unsigned* spos = (unsigned*)(smem + 3600);
    int t = threadIdx.x;
    for (int i = t; i < 512; i += 256) hist[i] = 0;
    if (t == 0) misc[1] = 0;
    __syncthreads();
    {   // inline dtype detection: odd int32 words nonzero => int32 storage
        int nz = (idx[2 * t + 1] != 0) + (idx[2 * t + 513] != 0);
        if (nz) atomicAdd(&misc[1], nz);
    }
    __syncthreads();
    int flag = (misc[1] > 16) ? 1 : 0;   // 1 => int32, 0 => int64 storage
    int e0 = blk * (256 * EPT);
    int EN = E + N;
    unsigned ent[EPT];
    int bid[EPT];
    int loc[EPT];
#pragma unroll
    for (int k = 0; k < EPT; k++) {
        int e = e0 + k * 256 + t;
        bid[k] = -1;
        if (e < EN) {
            int src, dst;
            if (e < E) {
                if (flag) { src = idx[e]; dst = idx[E + e]; }
                else      { src = idx[2 * e]; dst = idx[2 * (E + e)]; }
            } else {
                src = dst = e - E;
            }
            int b = dst >> BSHIFT;
            bid[k] = b;
            ent[k] = ((unsigned)(dst & ((1 << BSHIFT) - 1)) << 16) | (unsigned)src;
            loc[k] = atomicAdd(&hist[b], 1);
        }
    }
    __syncthreads();
    // exclusive scan of hist[0..512): 256 threads x 2 consecutive elements
    int i0 = 2 * t;
    int a = hist[i0], b2 = hist[i0 + 1];
    int ps = a + b2;
    int lane = t & 63, w = t >> 6;
    int incl = ps;
#pragma unroll
    for (int off = 1; off < 64; off <<= 1) {
        int u = __shfl_up(incl, off, 64);
        if (lane >= off) incl += u;
    }
    if (lane == 63) wtot[w] = incl;
    __syncthreads();
    int woff = 0;
    for (int k = 0; k < w; k++) woff += wtot[k];
    int ex0 = woff + incl - ps;
    lbase[i0] = ex0;
    lbase[i0 + 1] = ex0 + a;
    if (t == 255) misc[0] = woff + incl;
    for (int i = t; i < 512; i += 256) {
        int c = hist[i];
        gbase[i] = c ? atomicAdd(&gcursor[i], c) : 0;
    }
    __syncthreads();
#pragma unroll
    for (int k = 0; k < EPT; k++) {
        if (bid[k] >= 0) {
            int p = lbase[bid[k]] + loc[k];
            int pib = gbase[bid[k]] + loc[k];
            sent[p] = ent[k];
            spos[p] = (pib < BCAP) ? (((unsigned)bid[k] << BCAPSHIFT) | (unsigned)pib)
                                   : 0xFFFFFFFFu;
        }
    }
    __syncthreads();
    int tot = misc[0];
    for (int i = t; i < tot; i += 256) {
        unsigned sp = spos[i];
        if (sp != 0xFFFFFFFFu) bucket_buf[sp] = sent[i];
    }
}

// ---------------- K1 path B: MFMA GEMM1 + LDS-staged epilogue ---------------
__device__ __forceinline__ void gemm1_body(
    int blk, char* smemraw, const float* __restrict__ x, const short* __restrict__ w1t,
    const float* __restrict__ a_s, const float* __restrict__ a_d,
    unsigned short* __restrict__ h1g, unsigned short* __restrict__ asb,
    float* __restrict__ ad_n, int N) {
    short* Wt = (short*)smemraw;        // 128 x 128 bf16, swizzled
    float* hT = (float*)smemraw;        // 64 x 128 f32, swizzled (overlay)
    int t = threadIdx.x;
    const uint4* src = (const uint4*)w1t;
    for (int id = t; id < 128 * 16; id += 256) {
        int n = id >> 4, kg = id & 15;
        *(uint4*)&Wt[n * 128 + ((kg * 8) ^ ((n & 7) << 3))] = src[id];
    }
    __syncthreads();
    int wv = t >> 6, lane = t & 63;
    int m = lane & 15, q = lane >> 4;
    int row = blk * 64 + wv * 16 + m;
    f32x4 acc[8];
#pragma unroll
    for (int j = 0; j < 8; j++) acc[j] = (f32x4){0.f, 0.f, 0.f, 0.f};
    int msw = (m & 7) << 3;
#pragma unroll
    for (int k0 = 0; k0 < 128; k0 += 32) {
        bf16x8 a = {0, 0, 0, 0, 0, 0, 0, 0};
        if (row < N) {
            const float* xp = &x[(size_t)row * 128 + k0 + q * 8];
            float4 u0 = *(const float4*)xp;
            float4 u1 = *(const float4*)(xp + 4);
            a[0] = (short)f2bf(u0.x); a[1] = (short)f2bf(u0.y);
            a[2] = (short)f2bf(u0.z); a[3] = (short)f2bf(u0.w);
            a[4] = (short)f2bf(u1.x); a[5] = (short)f2bf(u1.y);
            a[6] = (short)f2bf(u1.z); a[7] = (short)f2bf(u1.w);
        }
#pragma unroll
        for (int j = 0; j < 8; j++) {
            bf16x8 b = *(const bf16x8*)&Wt[(j * 16 + m) * 128 + ((k0 + q * 8) ^ msw)];
            acc[j] = __builtin_amdgcn_mfma_f32_16x16x32_bf16(a, b, acc[j], 0, 0, 0);
        }
    }
    __syncthreads();                    // Wt dead; hT overlays it
#pragma unroll
    for (int r = 0; r < 4; r++) {
        int rl = wv * 16 + q * 4 + r;
        int sw = ((rl >> 2) & 1) << 4;
        int rb = rl * 128;
#pragma unroll
        for (int j = 0; j < 8; j++)
            hT[rb + ((j * 16 + m) ^ sw)] = acc[j][r];
    }
    __syncthreads();
    int base = blk * 64;
    // coalesced h1g flush: 1024 uint4 (8 bf16 each)
    for (int id = t; id < 1024; id += 256) {
        int rl = id >> 4, c8 = (id & 15) * 8;
        int rg = base + rl;
        if (rg >= N) continue;
        int sw = ((rl >> 2) & 1) << 4;
        float4 u0 = *(const float4*)&hT[rl * 128 + (c8 ^ sw)];
        float4 u1 = *(const float4*)&hT[rl * 128 + ((c8 + 4) ^ sw)];
        uint4 ow;
        ow.x = (unsigned)f2bf(u0.x) | ((unsigned)f2bf(u0.y) << 16);
        ow.y = (unsigned)f2bf(u0.z) | ((unsigned)f2bf(u0.w) << 16);
        ow.z = (unsigned)f2bf(u1.x) | ((unsigned)f2bf(u1.y) << 16);
        ow.w = (unsigned)f2bf(u1.z) | ((unsigned)f2bf(u1.w) << 16);
        *(uint4*)&h1g[(size_t)rg * 128 + c8] = ow;
    }
    // alpha pass: 512 items = 64 rows x 8 heads; as -> bf16 table, ad -> f32
    for (int it = t; it < 512; it += 256) {
        int rl = it >> 3, hd = it & 7;
        int rg = base + rl;
        int sw = ((rl >> 2) & 1) << 4;
        const float* ap = a_s + hd * 16;
        const float* dp = a_d + hd * 16;
        float s = 0.f, d = 0.f;
#pragma unroll
        for (int p = 0; p < 4; p++) {
            float4 u = *(const float4*)&hT[rl * 128 + ((hd * 16 + p * 4) ^ sw)];
            s += u.x * ap[p * 4] + u.y * ap[p * 4 + 1] + u.z * ap[p * 4 + 2] + u.w * ap[p * 4 + 3];
            d += u.x * dp[p * 4] + u.y * dp[p * 4 + 1] + u.z * dp[p * 4 + 2] + u.w * dp[p * 4 + 3];
        }
        if (rg < N) {
            asb[(size_t)base * 8 + it] = f2bf(s);    // bf16: halves mid's alpha gather
            ad_n[(size_t)base * 8 + it] = d;
        }
    }
}

__global__ __launch_bounds__(256) void k1_kernel(
    const int* __restrict__ idx, int* __restrict__ gcursor,
    unsigned* __restrict__ bucket_buf,
    const float* __restrict__ x, const short* __restrict__ w1t,
    const float* __restrict__ a_s, const float* __restrict__ a_d,
    unsigned short* __restrict__ h1g, unsigned short* __restrict__ asb,
    float* __restrict__ ad_n, int E, int N, int NB, int GS) {
    __shared__ long long smem[4096];   // 32768 B union: Wt/hT | bscatter (22.6 KB)
    if ((int)blockIdx.x < GS)
        bscatter_body(blockIdx.x, (int*)smem, idx, gcursor, bucket_buf, E, N, NB);
    else
        gemm1_body(blockIdx.x - GS, (char*)smem, x, w1t, a_s, a_d, h1g, asb, ad_n, N);
}

// ---------------- K2: per-bucket sort, LDS-staged coalesced flush ------------
__device__ __forceinline__ void bsort_body(
    int b, const int* __restrict__ gcursor, const unsigned* __restrict__ bucket_buf,
    int* __restrict__ row_start, int* __restrict__ sorted_src, int N, int NB) {
    __shared__ int cnt[128];
    __shared__ int cur[128];
    __shared__ int red[4];
    __shared__ int s_w0;
    __shared__ int srt[BCAP];
    int t = threadIdx.x;
    if (t < 128) cnt[t] = 0;
    int partial = 0;
    for (int i = t; i < b; i += 256) partial += min(gcursor[i], BCAP);
#pragma unroll
    for (int msk = 32; msk > 0; msk >>= 1) partial += __shfl_xor(partial, msk, 64);
    if ((t & 63) == 0) red[t >> 6] = partial;
    __syncthreads();
    int bbase = red[0] + red[1] + red[2] + red[3];
    int c = min(gcursor[b], BCAP);
    const unsigned* buf = bucket_buf + ((size_t)b << BCAPSHIFT);
    for (int i = t; i < c; i += 256)
        atomicAdd(&cnt[(buf[i] >> 16) & 127], 1);
    __syncthreads();
    int v = (t < 128) ? cnt[t] : 0;
    int lane = t & 63;
    int incl = v;
#pragma unroll
    for (int off = 1; off < 64; off <<= 1) {
        int u = __shfl_up(incl, off, 64);
        if (lane >= off) incl += u;
    }
    if (t == 63) s_w0 = incl;
    __syncthreads();
    if (t < 128) {
        int excl = incl - v + ((t >= 64) ? s_w0 : 0);
        cur[t] = excl;
        int node = (b << BSHIFT) + t;
        if (node <= N) row_start[node] = bbase + excl;
    }
    __syncthreads();
    for (int i = t; i < c; i += 256) {
        unsigned e = buf[i];
        int lp = atomicAdd(&cur[(e >> 16) & 127], 1);
        srt[lp] = (int)(e & 0xFFFFu);
    }
    __syncthreads();
    for (int i = t; i < c; i += 256)
        sorted_src[bbase + i] = srt[i];     // coalesced flush
}

__global__ __launch_bounds__(256) void k2_kernel(
    const int* __restrict__ gcursor, const unsigned* __restrict__ bucket_buf,
    int* __restrict__ row_start, int* __restrict__ sorted_src,
    int N, int NB, int EN) {
    if (blockIdx.x == 0 && threadIdx.x < 16) sorted_src[EN + threadIdx.x] = 0;  // pad
    bsort_body(blockIdx.x, gcursor, bucket_buf, row_start, sorted_src, N, NB);
}

// ---------------- mid: fused agg1 + GEMM2, 32-node tiles ---------------------
// Round-8: mid is latency-bound (occupancy 23.5%, fetch rate 2.2 TB/s << any
// ceiling). 32-node tiles double the grid (1563 blocks) and halve per-group
// serial work (2 nodes/group); LDS ~26 KB -> 6 blocks/CU residency. Inner edge
// loop is byte-identical to the proven round-6 version.
__global__ __launch_bounds__(256) void mid_kernel(
    const int* __restrict__ row_start, const int* __restrict__ sorted_src,
    const unsigned short* __restrict__ asb, const float* __restrict__ ad_n,
    const unsigned short* __restrict__ h1g, const float* __restrict__ b1,
    const short* __restrict__ w2t, const float* __restrict__ a_s2,
    const float* __restrict__ a_d2, unsigned short* __restrict__ h2g,
    float* __restrict__ as2n, float* __restrict__ ad2n, int N) {
    __shared__ short hA[32 * 128];      // h1act tile, XOR-swizzled (granule^=(row&7))
    __shared__ short Wt[64 * 136];      // W2^T tile
    __shared__ float sP[2][32];
    __shared__ float dP[2][32];
    int t = threadIdx.x;
    const uint4* srcw = (const uint4*)w2t;
    for (int id = t; id < 64 * 16; id += 256) {
        int n = id >> 4, kg = id & 15;
        *(uint4*)&Wt[n * 136 + kg * 8] = srcw[id];
    }
    int lane = t & 63;
    int g = lane >> 4, j = lane & 15;
    int base = blockIdx.x * 32;
    int grp16 = (t >> 6) * 4 + g;       // 0..15
    // ---- phase A: aggregate 2 nodes per group ----
    int e4 = j >> 2;
    int hh = (j & 3) * 2;
    int hd = j >> 1;
    int hsel = hd & 1;
    int wsrc = hd >> 1;
    for (int ni = 0; ni < 2; ni++) {
        int rowl = ni * 16 + grp16;
        int node = base + rowl;
        float acc[8];
#pragma unroll
        for (int k = 0; k < 8; k++) acc[k] = 0.f;
        float denom = 0.f;
        if (node < N) {
            float2 adp = *(const float2*)&ad_n[(size_t)node * 8 + hh];
            int beg = row_start[node], end = row_start[node + 1];
            for (int i = beg; i < end; i += 4) {
                int se = sorted_src[i + e4];
                unsigned au = *(const unsigned*)&asb[(size_t)se * 8 + hh];
                float w0 = __expf(lrelu(bf2f(au & 0xffffu) + adp.x));
                float w1 = __expf(lrelu(bf2f(au >> 16) + adp.y));
                bool val = (i + e4 < end);
                w0 = val ? w0 : 0.f;
                w1 = val ? w1 : 0.f;
#pragma unroll
                for (int e = 0; e < 4; e++) {
                    int sl = e * 4 + wsrc;
                    int sg = __shfl(se, sl, 16);
                    float wa = __shfl(w0, sl, 16);
                    float wb = __shfl(w1, sl, 16);
                    float wv = hsel ? wb : wa;
                    uint4 hv = *(const uint4*)&h1g[(size_t)sg * 128 + j * 8];
                    acc[0] += wv * bf2f(hv.x & 0xffffu);
                    acc[1] += wv * bf2f(hv.x >> 16);
                    acc[2] += wv * bf2f(hv.y & 0xffffu);
                    acc[3] += wv * bf2f(hv.y >> 16);
                    acc[4] += wv * bf2f(hv.z & 0xffffu);
                    acc[5] += wv * bf2f(hv.z >> 16);
                    acc[6] += wv * bf2f(hv.w & 0xffffu);
                    acc[7] += wv * bf2f(hv.w >> 16);
                    denom += wv;
                }
            }
        }
        float inv = 1.f / (denom + 1e-16f);
        int c0 = j * 8;
        unsigned ow[4];
#pragma unroll
        for (int p = 0; p < 4; p++) {
            float v0 = acc[2 * p] * inv + b1[c0 + 2 * p];
            float v1 = acc[2 * p + 1] * inv + b1[c0 + 2 * p + 1];
            v0 = (v0 > 0.f) ? v0 : (__expf(v0) - 1.f);
            v1 = (v1 > 0.f) ? v1 : (__expf(v1) - 1.f);
            ow[p] = (unsigned)f2bf(v0) | ((unsigned)f2bf(v1) << 16);
        }
        uint4 val = (node < N) ? make_uint4(ow[0], ow[1], ow[2], ow[3])
                               : make_uint4(0, 0, 0, 0);
        *(uint4*)&hA[rowl * 128 + ((j * 8) ^ ((rowl & 7) << 3))] = val;
    }
    __syncthreads();
    // ---- phase B: gemm2, 4 waves = 2 row tiles x 2 column pairs ----
    int wv = t >> 6;            // 0..3
    int rt = wv & 1;            // row tile
    int cp = wv >> 1;           // column pair: j4 in {2cp, 2cp+1}
    int m = lane & 15, q = lane >> 4;
    int rowl = rt * 16 + m;
    int rsw = (rowl & 7) << 3;
    f32x4 acc2[2];
#pragma unroll
    for (int jj = 0; jj < 2; jj++) acc2[jj] = (f32x4){0.f, 0.f, 0.f, 0.f};
#pragma unroll
    for (int k0 = 0; k0 < 128; k0 += 32) {
        bf16x8 a = *(const bf16x8*)&hA[rowl * 128 + ((k0 + q * 8) ^ rsw)];
#pragma unroll
        for (int jj = 0; jj < 2; jj++) {
            int j4 = cp * 2 + jj;
            bf16x8 b = *(const bf16x8*)&Wt[(j4 * 16 + m) * 136 + k0 + q * 8];
            acc2[jj] = __builtin_amdgcn_mfma_f32_16x16x32_bf16(a, b, acc2[jj], 0, 0, 0);
        }
    }
    float asl[2], adl[2];
#pragma unroll
    for (int jj = 0; jj < 2; jj++) {
        asl[jj] = a_s2[(cp * 2 + jj) * 16 + m];
        adl[jj] = a_d2[(cp * 2 + jj) * 16 + m];
    }
    int rb = rt * 16 + q * 4;
#pragma unroll
    for (int r = 0; r < 4; r++) {
        int rl2 = rb + r;
        int rr = base + rl2;
        float s = 0.f, d = 0.f;
#pragma unroll
        for (int jj = 0; jj < 2; jj++) {
            s += acc2[jj][r] * asl[jj];
            d += acc2[jj][r] * adl[jj];
        }
#pragma unroll
        for (int msk = 8; msk > 0; msk >>= 1) {
            s += __shfl_xor(s, msk, 64);
            d += __shfl_xor(d, msk, 64);
        }
        if (rr < N) {
            if (m == 0) { sP[cp][rl2] = s; dP[cp][rl2] = d; }
#pragma unroll
            for (int jj = 0; jj < 2; jj++)
                h2g[(size_t)rr * 64 + (cp * 2 + jj) * 16 + m] = f2bf(acc2[jj][r]);
        }
    }
    __syncthreads();
    if (t < 32) {
        int rr = base + t;
        if (rr < N) {
            as2n[rr] = sP[0][t] + sP[1][t];
            ad2n[rr] = dP[0][t] + dP[1][t];
        }
    }
}

// ---------------- layer-2 aggregation + log_softmax: group/node, 4 edges/iter
__global__ __launch_bounds__(256) void agg2_kernel(
    const int* __restrict__ row_start, const int* __restrict__ sorted_src,
    const float* __restrict__ as_n, const float* __restrict__ ad_n,
    const unsigned short* __restrict__ h2g, const float* __restrict__ b2,
    float* __restrict__ out, int N) {
    int lane = threadIdx.x & 63;
    int g = lane >> 4, j = lane & 15;
    int node = blockIdx.x * 16 + (threadIdx.x >> 6) * 4 + g;
    if (node >= N) return;
    int e4 = j >> 2;
    float adv = ad_n[node];
    int beg = row_start[node], end = row_start[node + 1];
    float acc[4];
#pragma unroll
    for (int k = 0; k < 4; k++) acc[k] = 0.f;
    float denom = 0.f;
    for (int i = beg; i < end; i += 4) {
        int se = sorted_src[i + e4];
        float w = __expf(lrelu(as_n[se] + adv));
        w = (i + e4 < end) ? w : 0.f;
#pragma unroll
        for (int e = 0; e < 4; e++) {
            int sg = __shfl(se, e * 4, 16);
            float wvv = __shfl(w, e * 4, 16);
            uint2 hv = *(const uint2*)&h2g[(size_t)sg * 64 + j * 4];
            acc[0] += wvv * bf2f(hv.x & 0xffffu);
            acc[1] += wvv * bf2f(hv.x >> 16);
            acc[2] += wvv * bf2f(hv.y & 0xffffu);
            acc[3] += wvv * bf2f(hv.y >> 16);
            denom += wvv;
        }
    }
    float inv = 1.f / (denom + 1e-16f);
    int c0 = j * 4;
    float v[4];
#pragma unroll
    for (int k = 0; k < 4; k++) v[k] = acc[k] * inv + b2[c0 + k];
    float mx = fmaxf(fmaxf(v[0], v[1]), fmaxf(v[2], v[3]));
#pragma unroll
    for (int msk = 8; msk > 0; msk >>= 1) mx = fmaxf(mx, __shfl_xor(mx, msk, 64));
    float ex = __expf(v[0] - mx) + __expf(v[1] - mx) + __expf(v[2] - mx) + __expf(v[3] - mx);
#pragma unroll
    for (int msk = 8; msk > 0; msk >>= 1) ex += __shfl_xor(ex, msk, 64);
    float lse = mx + __logf(ex);
    *(float4*)&out[(size_t)node * 64 + c0] = make_float4(v[0] - lse, v[1] - lse, v[2] - lse, v[3] - lse);
}

extern "C" void kernel_launch(void* const* d_in, const int* in_sizes, int n_in,
                              void* d_out, int out_size, void* d_ws, size_t ws_size,
                              hipStream_t stream) {
    const float* x   = (const float*)d_in[0];
    const int*   idx = (const int*)d_in[1];
    const float* W1  = (const float*)d_in[2];
    const float* as1 = (const float*)d_in[3];
    const float* ad1 = (const float*)d_in[4];
    const float* b1  = (const float*)d_in[5];
    const float* W2  = (const float*)d_in[6];
    const float* as2 = (const float*)d_in[7];
    const float* ad2 = (const float*)d_in[8];
    const float* b2  = (const float*)d_in[9];
    float* out = (float*)d_out;

    const int N = in_sizes[0] / IN_DIM;
    const int E = in_sizes[1] / 2;
    const int EN = E + N;
    const int NB = (N + (1 << BSHIFT) - 1) >> BSHIFT;   // buckets
    const int GS = (EN + 256 * EPT - 1) / (256 * EPT);  // bscatter blocks
    const int T1 = (N + 63) / 64;                        // gemm1 tiles
    const int T2 = (N + 31) / 32;                        // mid tiles

    // workspace layout (h1act slot retained but unused)
    unsigned short* h1g   = (unsigned short*)d_ws;          // N*128 bf16
    unsigned short* h1act = h1g + (size_t)N * 128;          // N*128 bf16 (unused)
    unsigned short* h2g   = h1act + (size_t)N * 128;        // N*64 bf16
    unsigned short* as1b  = (unsigned short*)(h2g + (size_t)N * 64);  // N*8 bf16 (in old f32 slot)
    float* ad1n = (float*)(as1b + (size_t)N * 8) + (size_t)N * 4;     // keep original ad1n offset
    float* as2n = ad1n + (size_t)N * 8;                     // N
    float* ad2n = as2n + (size_t)N;                         // N
    int* row_start  = (int*)(ad2n + (size_t)N);             // N+1
    int* gcursor    = row_start + N + 1;                    // 512
    unsigned* bucket_buf = (unsigned*)(gcursor + 512);      // NB*BCAP
    int* sorted_src = (int*)(bucket_buf + ((size_t)NB << BCAPSHIFT));  // E+N+16 (padded)
    short* w1t = (short*)((((uintptr_t)(sorted_src + EN + 16)) + 15) & ~(uintptr_t)15);  // 128x128 bf16
    short* w2t = w1t + 128 * 128;                            // 64x128 bf16
    (void)ws_size; (void)n_in; (void)out_size;

    setup_kernel<<<97, 256, 0, stream>>>(W1, W2, w1t, w2t, gcursor);
    k1_kernel<<<GS + T1, 256, 0, stream>>>(idx, gcursor, bucket_buf,
                                           x, w1t, as1, ad1, h1g, as1b, ad1n, E, N, NB, GS);
    k2_kernel<<<NB, 256, 0, stream>>>(gcursor, bucket_buf, row_start, sorted_src, N, NB, EN);
    mid_kernel<<<T2, 256, 0, stream>>>(row_start, sorted_src, as1b, ad1n, h1g, b1,
                                       w2t, as2, ad2, h2g, as2n, ad2n, N);
    agg2_kernel<<<(N + 15) / 16, 256, 0, stream>>>(row_start, sorted_src, as2n, ad2n, h2g, b2, out, N);
}

// Round 9
// 182.491 us; speedup vs baseline: 1.0243x; 1.0243x over previous
//
#include <hip/hip_runtime.h>
#include <hip/hip_bf16.h>
#include <math.h>

#define IN_DIM 128
#define HID 128
#define HEADS 8
#define OUT_DIM 64
#define SLOPE 0.2f
#define BSHIFT 7          // 128 nodes per bucket
#define BCAP 4096         // entries per bucket (mean ~2176)
#define BCAPSHIFT 12
#define EPT 8             // edges per thread in bscatter

typedef short bf16x8 __attribute__((ext_vector_type(8)));
typedef float f32x4 __attribute__((ext_vector_type(4)));

__device__ __forceinline__ float lrelu(float x) { return fmaxf(x, SLOPE * x); }
__device__ __forceinline__ float bf2f(unsigned u) { return __uint_as_float(u << 16); }
__device__ __forceinline__ unsigned short f2bf(float f) {
    unsigned u = __float_as_uint(f);
    return (unsigned short)((u + 0x7FFF + ((u >> 16) & 1)) >> 16);  // RNE
}

// ---------------- setup: zero gcursor + build bf16 transposed weights --------
__global__ __launch_bounds__(256) void setup_kernel(
    const float* __restrict__ W1, const float* __restrict__ W2,
    short* __restrict__ w1t, short* __restrict__ w2t, int* __restrict__ gcursor) {
    int t = threadIdx.x;
    int b = blockIdx.x;
    if (b == 96) {
        for (int i = t; i < 512; i += 256) gcursor[i] = 0;
        return;
    }
    if (b < 64) {
        int id = b * 256 + t;            // id = n*128 + k
        int n = id >> 7, k = id & 127;
        w1t[id] = (short)f2bf(W1[k * 128 + n]);
    } else {
        int id = (b - 64) * 256 + t;     // id = n*128 + k, n < 64
        int n = id >> 7, k = id & 127;
        w2t[id] = (short)f2bf(W2[k * 64 + n]);
    }
}

// ---------------- K1 path A: bucket scatter with block-local counting sort ---
__device__ __forceinline__ void bscatter_body(
    int blk, int* smem, const int* __restrict__ idx,
    int* __restrict__ gcursor, unsigned* __restrict__ bucket_buf,
    int E, int N, int NB) {
    int* hist  = smem;
    int* gbase = smem + 512;
    int* lbase = smem + 1024;
    int* wtot  = smem + 1536;
    int* misc  = smem + 1540;     // [0]=total, [1]=nz
    unsigned* sent = (unsigned*)(smem + 1552);
    unsigned* spos = (unsigned*)(smem + 3600);
    int t = threadIdx.x;
    for (int i = t; i < 512; i += 256) hist[i] = 0;
    if (t == 0) misc[1] = 0;
    __syncthreads();
    {   // inline dtype detection: odd int32 words nonzero => int32 storage
        int nz = (idx[2 * t + 1] != 0) + (idx[2 * t + 513] != 0);
        if (nz) atomicAdd(&misc[1], nz);
    }
    __syncthreads();
    int flag = (misc[1] > 16) ? 1 : 0;   // 1 => int32, 0 => int64 storage
    int e0 = blk * (256 * EPT);
    int EN = E + N;
    unsigned ent[EPT];
    int bid[EPT];
    int loc[EPT];
#pragma unroll
    for (int k = 0; k < EPT; k++) {
        int e = e0 + k * 256 + t;
        bid[k] = -1;
        if (e < EN) {
            int src, dst;
            if (e < E) {
                if (flag) { src = idx[e]; dst = idx[E + e]; }
                else      { src = idx[2 * e]; dst = idx[2 * (E + e)]; }
            } else {
                src = dst = e - E;
            }
            int b = dst >> BSHIFT;
            bid[k] = b;
            ent[k] = ((unsigned)(dst & ((1 << BSHIFT) - 1)) << 16) | (unsigned)src;
            loc[k] = atomicAdd(&hist[b], 1);
        }
    }
    __syncthreads();
    // exclusive scan of hist[0..512): 256 threads x 2 consecutive elements
    int i0 = 2 * t;
    int a = hist[i0], b2 = hist[i0 + 1];
    int ps = a + b2;
    int lane = t & 63, w = t >> 6;
    int incl = ps;
#pragma unroll
    for (int off = 1; off < 64; off <<= 1) {
        int u = __shfl_up(incl, off, 64);
        if (lane >= off) incl += u;
    }
    if (lane == 63) wtot[w] = incl;
    __syncthreads();
    int woff = 0;
    for (int k = 0; k < w; k++) woff += wtot[k];
    int ex0 = woff + incl - ps;
    lbase[i0] = ex0;
    lbase[i0 + 1] = ex0 + a;
    if (t == 255) misc[0] = woff + incl;
    for (int i = t; i < 512; i += 256) {
        int c = hist[i];
        gbase[i] = c ? atomicAdd(&gcursor[i], c) : 0;
    }
    __syncthreads();
#pragma unroll
    for (int k = 0; k < EPT; k++) {
        if (bid[k] >= 0) {
            int p = lbase[bid[k]] + loc[k];
            int pib = gbase[bid[k]] + loc[k];
            sent[p] = ent[k];
            spos[p] = (pib < BCAP) ? (((unsigned)bid[k] << BCAPSHIFT) | (unsigned)pib)
                                   : 0xFFFFFFFFu;
        }
    }
    __syncthreads();
    int tot = misc[0];
    for (int i = t; i < tot; i += 256) {
        unsigned sp = spos[i];
        if (sp != 0xFFFFFFFFu) bucket_buf[sp] = sent[i];
    }
}

// ---------------- K1 path B: MFMA GEMM1 + LDS-staged epilogue ---------------
__device__ __forceinline__ void gemm1_body(
    int blk, char* smemraw, const float* __restrict__ x, const short* __restrict__ w1t,
    const float* __restrict__ a_s, const float* __restrict__ a_d,
    unsigned short* __restrict__ h1g, unsigned short* __restrict__ asb,
    float* __restrict__ ad_n, int N) {
    short* Wt = (short*)smemraw;        // 128 x 128 bf16, swizzled
    float* hT = (float*)smemraw;        // 64 x 128 f32, swizzled (overlay)
    int t = threadIdx.x;
    const uint4* src = (const uint4*)w1t;
    for (int id = t; id < 128 * 16; id += 256) {
        int n = id >> 4, kg = id & 15;
        *(uint4*)&Wt[n * 128 + ((kg * 8) ^ ((n & 7) << 3))] = src[id];
    }
    __syncthreads();
    int wv = t >> 6, lane = t & 63;
    int m = lane & 15, q = lane >> 4;
    int row = blk * 64 + wv * 16 + m;
    f32x4 acc[8];
#pragma unroll
    for (int j = 0; j < 8; j++) acc[j] = (f32x4){0.f, 0.f, 0.f, 0.f};
    int msw = (m & 7) << 3;
#pragma unroll
    for (int k0 = 0; k0 < 128; k0 += 32) {
        bf16x8 a = {0, 0, 0, 0, 0, 0, 0, 0};
        if (row < N) {
            const float* xp = &x[(size_t)row * 128 + k0 + q * 8];
            float4 u0 = *(const float4*)xp;
            float4 u1 = *(const float4*)(xp + 4);
            a[0] = (short)f2bf(u0.x); a[1] = (short)f2bf(u0.y);
            a[2] = (short)f2bf(u0.z); a[3] = (short)f2bf(u0.w);
            a[4] = (short)f2bf(u1.x); a[5] = (short)f2bf(u1.y);
            a[6] = (short)f2bf(u1.z); a[7] = (short)f2bf(u1.w);
        }
#pragma unroll
        for (int j = 0; j < 8; j++) {
            bf16x8 b = *(const bf16x8*)&Wt[(j * 16 + m) * 128 + ((k0 + q * 8) ^ msw)];
            acc[j] = __builtin_amdgcn_mfma_f32_16x16x32_bf16(a, b, acc[j], 0, 0, 0);
        }
    }
    __syncthreads();                    // Wt dead; hT overlays it
#pragma unroll
    for (int r = 0; r < 4; r++) {
        int rl = wv * 16 + q * 4 + r;
        int sw = ((rl >> 2) & 1) << 4;
        int rb = rl * 128;
#pragma unroll
        for (int j = 0; j < 8; j++)
            hT[rb + ((j * 16 + m) ^ sw)] = acc[j][r];
    }
    __syncthreads();
    int base = blk * 64;
    // coalesced h1g flush: 1024 uint4 (8 bf16 each)
    for (int id = t; id < 1024; id += 256) {
        int rl = id >> 4, c8 = (id & 15) * 8;
        int rg = base + rl;
        if (rg >= N) continue;
        int sw = ((rl >> 2) & 1) << 4;
        float4 u0 = *(const float4*)&hT[rl * 128 + (c8 ^ sw)];
        float4 u1 = *(const float4*)&hT[rl * 128 + ((c8 + 4) ^ sw)];
        uint4 ow;
        ow.x = (unsigned)f2bf(u0.x) | ((unsigned)f2bf(u0.y) << 16);
        ow.y = (unsigned)f2bf(u0.z) | ((unsigned)f2bf(u0.w) << 16);
        ow.z = (unsigned)f2bf(u1.x) | ((unsigned)f2bf(u1.y) << 16);
        ow.w = (unsigned)f2bf(u1.z) | ((unsigned)f2bf(u1.w) << 16);
        *(uint4*)&h1g[(size_t)rg * 128 + c8] = ow;
    }
    // alpha pass: 512 items = 64 rows x 8 heads; as -> bf16 table, ad -> f32
    for (int it = t; it < 512; it += 256) {
        int rl = it >> 3, hd = it & 7;
        int rg = base + rl;
        int sw = ((rl >> 2) & 1) << 4;
        const float* ap = a_s + hd * 16;
        const float* dp = a_d + hd * 16;
        float s = 0.f, d = 0.f;
#pragma unroll
        for (int p = 0; p < 4; p++) {
            float4 u = *(const float4*)&hT[rl * 128 + ((hd * 16 + p * 4) ^ sw)];
            s += u.x * ap[p * 4] + u.y * ap[p * 4 + 1] + u.z * ap[p * 4 + 2] + u.w * ap[p * 4 + 3];
            d += u.x * dp[p * 4] + u.y * dp[p * 4 + 1] + u.z * dp[p * 4 + 2] + u.w * dp[p * 4 + 3];
        }
        if (rg < N) {
            asb[(size_t)base * 8 + it] = f2bf(s);    // bf16: halves mid's alpha gather
            ad_n[(size_t)base * 8 + it] = d;
        }
    }
}

__global__ __launch_bounds__(256) void k1_kernel(
    const int* __restrict__ idx, int* __restrict__ gcursor,
    unsigned* __restrict__ bucket_buf,
    const float* __restrict__ x, const short* __restrict__ w1t,
    const float* __restrict__ a_s, const float* __restrict__ a_d,
    unsigned short* __restrict__ h1g, unsigned short* __restrict__ asb,
    float* __restrict__ ad_n, int E, int N, int NB, int GS) {
    __shared__ long long smem[4096];   // 32768 B union: Wt/hT | bscatter (22.6 KB)
    if ((int)blockIdx.x < GS)
        bscatter_body(blockIdx.x, (int*)smem, idx, gcursor, bucket_buf, E, N, NB);
    else
        gemm1_body(blockIdx.x - GS, (char*)smem, x, w1t, a_s, a_d, h1g, asb, ad_n, N);
}

// ---------------- K2: per-bucket sort, LDS-staged coalesced flush ------------
__device__ __forceinline__ void bsort_body(
    int b, const int* __restrict__ gcursor, const unsigned* __restrict__ bucket_buf,
    int* __restrict__ row_start, int* __restrict__ sorted_src, int N, int NB) {
    __shared__ int cnt[128];
    __shared__ int cur[128];
    __shared__ int red[4];
    __shared__ int s_w0;
    __shared__ int srt[BCAP];
    int t = threadIdx.x;
    if (t < 128) cnt[t] = 0;
    int partial = 0;
    for (int i = t; i < b; i += 256) partial += min(gcursor[i], BCAP);
#pragma unroll
    for (int msk = 32; msk > 0; msk >>= 1) partial += __shfl_xor(partial, msk, 64);
    if ((t & 63) == 0) red[t >> 6] = partial;
    __syncthreads();
    int bbase = red[0] + red[1] + red[2] + red[3];
    int c = min(gcursor[b], BCAP);
    const unsigned* buf = bucket_buf + ((size_t)b << BCAPSHIFT);
    for (int i = t; i < c; i += 256)
        atomicAdd(&cnt[(buf[i] >> 16) & 127], 1);
    __syncthreads();
    int v = (t < 128) ? cnt[t] : 0;
    int lane = t & 63;
    int incl = v;
#pragma unroll
    for (int off = 1; off < 64; off <<= 1) {
        int u = __shfl_up(incl, off, 64);
        if (lane >= off) incl += u;
    }
    if (t == 63) s_w0 = incl;
    __syncthreads();
    if (t < 128) {
        int excl = incl - v + ((t >= 64) ? s_w0 : 0);
        cur[t] = excl;
        int node = (b << BSHIFT) + t;
        if (node <= N) row_start[node] = bbase + excl;
    }
    __syncthreads();
    for (int i = t; i < c; i += 256) {
        unsigned e = buf[i];
        int lp = atomicAdd(&cur[(e >> 16) & 127], 1);
        srt[lp] = (int)(e & 0xFFFFu);
    }
    __syncthreads();
    for (int i = t; i < c; i += 256)
        sorted_src[bbase + i] = srt[i];     // coalesced flush
}

__global__ __launch_bounds__(256) void k2_kernel(
    const int* __restrict__ gcursor, const unsigned* __restrict__ bucket_buf,
    int* __restrict__ row_start, int* __restrict__ sorted_src,
    int N, int NB, int EN) {
    if (blockIdx.x == 0 && threadIdx.x < 16) sorted_src[EN + threadIdx.x] = 0;  // pad
    bsort_body(blockIdx.x, gcursor, bucket_buf, row_start, sorted_src, N, NB);
}

// ---------------- mid: fused layer-1 aggregation + GEMM2 (round-4 shape) -----
// At the random-gather sweep floor: FETCH ~96 MB (8 XCD L2s x h1g 12.8 MB),
// effective 2.4 TB/s across occupancy 23-34% (r5/r8 refuted parallelism axis).
__global__ __launch_bounds__(256) void mid_kernel(
    const int* __restrict__ row_start, const int* __restrict__ sorted_src,
    const unsigned short* __restrict__ asb, const float* __restrict__ ad_n,
    const unsigned short* __restrict__ h1g, const float* __restrict__ b1,
    const short* __restrict__ w2t, const float* __restrict__ a_s2,
    const float* __restrict__ a_d2, unsigned short* __restrict__ h2g,
    float* __restrict__ as2n, float* __restrict__ ad2n, int N) {
    __shared__ short hA[64 * 128];      // h1act tile, XOR-swizzled (granule^=(row&7))
    __shared__ short Wt[64 * 136];      // W2^T tile
    int t = threadIdx.x;
    const uint4* srcw = (const uint4*)w2t;
    for (int id = t; id < 64 * 16; id += 256) {
        int n = id >> 4, kg = id & 15;
        *(uint4*)&Wt[n * 136 + kg * 8] = srcw[id];
    }
    int lane = t & 63;
    int g = lane >> 4, j = lane & 15;
    int base = blockIdx.x * 64;
    int grp16 = (t >> 6) * 4 + g;       // 0..15
    // ---- phase A: aggregate 4 nodes per group ----
    int e4 = j >> 2;
    int hh = (j & 3) * 2;
    int hd = j >> 1;
    int hsel = hd & 1;
    int wsrc = hd >> 1;
    for (int ni = 0; ni < 4; ni++) {
        int rowl = ni * 16 + grp16;
        int node = base + rowl;
        float acc[8];
#pragma unroll
        for (int k = 0; k < 8; k++) acc[k] = 0.f;
        float denom = 0.f;
        if (node < N) {
            float2 adp = *(const float2*)&ad_n[(size_t)node * 8 + hh];
            int beg = row_start[node], end = row_start[node + 1];
            for (int i = beg; i < end; i += 4) {
                int se = sorted_src[i + e4];
                unsigned au = *(const unsigned*)&asb[(size_t)se * 8 + hh];
                float w0 = __expf(lrelu(bf2f(au & 0xffffu) + adp.x));
                float w1 = __expf(lrelu(bf2f(au >> 16) + adp.y));
                bool val = (i + e4 < end);
                w0 = val ? w0 : 0.f;
                w1 = val ? w1 : 0.f;
#pragma unroll
                for (int e = 0; e < 4; e++) {
                    int sl = e * 4 + wsrc;
                    int sg = __shfl(se, sl, 16);
                    float wa = __shfl(w0, sl, 16);
                    float wb = __shfl(w1, sl, 16);
                    float wv = hsel ? wb : wa;
                    uint4 hv = *(const uint4*)&h1g[(size_t)sg * 128 + j * 8];
                    acc[0] += wv * bf2f(hv.x & 0xffffu);
                    acc[1] += wv * bf2f(hv.x >> 16);
                    acc[2] += wv * bf2f(hv.y & 0xffffu);
                    acc[3] += wv * bf2f(hv.y >> 16);
                    acc[4] += wv * bf2f(hv.z & 0xffffu);
                    acc[5] += wv * bf2f(hv.z >> 16);
                    acc[6] += wv * bf2f(hv.w & 0xffffu);
                    acc[7] += wv * bf2f(hv.w >> 16);
                    denom += wv;
                }
            }
        }
        float inv = 1.f / (denom + 1e-16f);
        int c0 = j * 8;
        unsigned ow[4];
#pragma unroll
        for (int p = 0; p < 4; p++) {
            float v0 = acc[2 * p] * inv + b1[c0 + 2 * p];
            float v1 = acc[2 * p + 1] * inv + b1[c0 + 2 * p + 1];
            v0 = (v0 > 0.f) ? v0 : (__expf(v0) - 1.f);
            v1 = (v1 > 0.f) ? v1 : (__expf(v1) - 1.f);
            ow[p] = (unsigned)f2bf(v0) | ((unsigned)f2bf(v1) << 16);
        }
        uint4 val = (node < N) ? make_uint4(ow[0], ow[1], ow[2], ow[3])
                               : make_uint4(0, 0, 0, 0);
        *(uint4*)&hA[rowl * 128 + ((j * 8) ^ ((rowl & 7) << 3))] = val;
    }
    __syncthreads();
    // ---- phase B: gemm2 on the 64-row LDS tile ----
    int wv = t >> 6;
    int m = lane & 15, q = lane >> 4;
    int rowl = wv * 16 + m;
    int rsw = (rowl & 7) << 3;
    f32x4 acc2[4];
#pragma unroll
    for (int j4 = 0; j4 < 4; j4++) acc2[j4] = (f32x4){0.f, 0.f, 0.f, 0.f};
#pragma unroll
    for (int k0 = 0; k0 < 128; k0 += 32) {
        bf16x8 a = *(const bf16x8*)&hA[rowl * 128 + ((k0 + q * 8) ^ rsw)];
#pragma unroll
        for (int j4 = 0; j4 < 4; j4++) {
            bf16x8 b = *(const bf16x8*)&Wt[(j4 * 16 + m) * 136 + k0 + q * 8];
            acc2[j4] = __builtin_amdgcn_mfma_f32_16x16x32_bf16(a, b, acc2[j4], 0, 0, 0);
        }
    }
    float asl[4], adl[4];
#pragma unroll
    for (int j4 = 0; j4 < 4; j4++) { asl[j4] = a_s2[j4 * 16 + m]; adl[j4] = a_d2[j4 * 16 + m]; }
    int rbase = base + wv * 16 + q * 4;
#pragma unroll
    for (int r = 0; r < 4; r++) {
        int rr = rbase + r;
        float s = 0.f, d = 0.f;
#pragma unroll
        for (int j4 = 0; j4 < 4; j4++) {
            s += acc2[j4][r] * asl[j4];
            d += acc2[j4][r] * adl[j4];
        }
#pragma unroll
        for (int msk = 8; msk > 0; msk >>= 1) {
            s += __shfl_xor(s, msk, 64);
            d += __shfl_xor(d, msk, 64);
        }
        if (rr < N) {
            if (m == 0) { as2n[rr] = s; ad2n[rr] = d; }
#pragma unroll
            for (int j4 = 0; j4 < 4; j4++)
                h2g[(size_t)rr * 64 + j4 * 16 + m] = f2bf(acc2[j4][r]);
        }
    }
}

// ---------------- layer-2 aggregation + log_softmax: group/node, 4 edges/iter
__global__ __launch_bounds__(256) void agg2_kernel(
    const int* __restrict__ row_start, const int* __restrict__ sorted_src,
    const float* __restrict__ as_n, const float* __restrict__ ad_n,
    const unsigned short* __restrict__ h2g, const float* __restrict__ b2,
    float* __restrict__ out, int N) {
    int lane = threadIdx.x & 63;
    int g = lane >> 4, j = lane & 15;
    int node = blockIdx.x * 16 + (threadIdx.x >> 6) * 4 + g;
    if (node >= N) return;
    int e4 = j >> 2;
    float adv = ad_n[node];
    int beg = row_start[node], end = row_start[node + 1];
    float acc[4];
#pragma unroll
    for (int k = 0; k < 4; k++) acc[k] = 0.f;
    float denom = 0.f;
    for (int i = beg; i < end; i += 4) {
        int se = sorted_src[i + e4];
        float w = __expf(lrelu(as_n[se] + adv));
        w = (i + e4 < end) ? w : 0.f;
#pragma unroll
        for (int e = 0; e < 4; e++) {
            int sg = __shfl(se, e * 4, 16);
            float wvv = __shfl(w, e * 4, 16);
            uint2 hv = *(const uint2*)&h2g[(size_t)sg * 64 + j * 4];
            acc[0] += wvv * bf2f(hv.x & 0xffffu);
            acc[1] += wvv * bf2f(hv.x >> 16);
            acc[2] += wvv * bf2f(hv.y & 0xffffu);
            acc[3] += wvv * bf2f(hv.y >> 16);
            denom += wvv;
        }
    }
    float inv = 1.f / (denom + 1e-16f);
    int c0 = j * 4;
    float v[4];
#pragma unroll
    for (int k = 0; k < 4; k++) v[k] = acc[k] * inv + b2[c0 + k];
    float mx = fmaxf(fmaxf(v[0], v[1]), fmaxf(v[2], v[3]));
#pragma unroll
    for (int msk = 8; msk > 0; msk >>= 1) mx = fmaxf(mx, __shfl_xor(mx, msk, 64));
    float ex = __expf(v[0] - mx) + __expf(v[1] - mx) + __expf(v[2] - mx) + __expf(v[3] - mx);
#pragma unroll
    for (int msk = 8; msk > 0; msk >>= 1) ex += __shfl_xor(ex, msk, 64);
    float lse = mx + __logf(ex);
    *(float4*)&out[(size_t)node * 64 + c0] = make_float4(v[0] - lse, v[1] - lse, v[2] - lse, v[3] - lse);
}

extern "C" void kernel_launch(void* const* d_in, const int* in_sizes, int n_in,
                              void* d_out, int out_size, void* d_ws, size_t ws_size,
                              hipStream_t stream) {
    const float* x   = (const float*)d_in[0];
    const int*   idx = (const int*)d_in[1];
    const float* W1  = (const float*)d_in[2];
    const float* as1 = (const float*)d_in[3];
    const float* ad1 = (const float*)d_in[4];
    const float* b1  = (const float*)d_in[5];
    const float* W2  = (const float*)d_in[6];
    const float* as2 = (const float*)d_in[7];
    const float* ad2 = (const float*)d_in[8];
    const float* b2  = (const float*)d_in[9];
    float* out = (float*)d_out;

    const int N = in_sizes[0] / IN_DIM;
    const int E = in_sizes[1] / 2;
    const int EN = E + N;
    const int NB = (N + (1 << BSHIFT) - 1) >> BSHIFT;   // buckets
    const int GS = (EN + 256 * EPT - 1) / (256 * EPT);  // bscatter blocks
    const int T1 = (N + 63) / 64;                        // gemm tiles

    // workspace layout (h1act slot retained but unused)
    unsigned short* h1g   = (unsigned short*)d_ws;          // N*128 bf16
    unsigned short* h1act = h1g + (size_t)N * 128;          // N*128 bf16 (unused)
    unsigned short* h2g   = h1act + (size_t)N * 128;        // N*64 bf16
    unsigned short* as1b  = (unsigned short*)(h2g + (size_t)N * 64);  // N*8 bf16 (in old f32 slot)
    float* ad1n = (float*)(as1b + (size_t)N * 8) + (size_t)N * 4;     // keep original ad1n offset
    float* as2n = ad1n + (size_t)N * 8;                     // N
    float* ad2n = as2n + (size_t)N;                         // N
    int* row_start  = (int*)(ad2n + (size_t)N);             // N+1
    int* gcursor    = row_start + N + 1;                    // 512
    unsigned* bucket_buf = (unsigned*)(gcursor + 512);      // NB*BCAP
    int* sorted_src = (int*)(bucket_buf + ((size_t)NB << BCAPSHIFT));  // E+N+16 (padded)
    short* w1t = (short*)((((uintptr_t)(sorted_src + EN + 16)) + 15) & ~(uintptr_t)15);  // 128x128 bf16
    short* w2t = w1t + 128 * 128;                            // 64x128 bf16
    (void)ws_size; (void)n_in; (void)out_size;

    setup_kernel<<<97, 256, 0, stream>>>(W1, W2, w1t, w2t, gcursor);
    k1_kernel<<<GS + T1, 256, 0, stream>>>(idx, gcursor, bucket_buf,
                                           x, w1t, as1, ad1, h1g, as1b, ad1n, E, N, NB, GS);
    k2_kernel<<<NB, 256, 0, stream>>>(gcursor, bucket_buf, row_start, sorted_src, N, NB, EN);
    mid_kernel<<<T1, 256, 0, stream>>>(row_start, sorted_src, as1b, ad1n, h1g, b1,
                                       w2t, as2, ad2, h2g, as2n, ad2n, N);
    agg2_kernel<<<(N + 15) / 16, 256, 0, stream>>>(row_start, sorted_src, as2n, ad2n, h2g, b2, out, N);
}